// Round 6
// baseline (413.909 us; speedup 1.0000x reference)
//
#include <hip/hip_runtime.h>
#include <stdint.h>

#define DM 1024      // d_model
#define HEADS 16
#define BATCH 8
#define SEQ 1024
#define MTOT 8192    // BATCH*SEQ

typedef _Float16 half8 __attribute__((ext_vector_type(8)));
typedef _Float16 half4 __attribute__((ext_vector_type(4)));
typedef float floatx4 __attribute__((ext_vector_type(4)));

// async global->LDS, 16B per lane. lds dest must be wave-uniform base; HW adds lane*16.
__device__ __forceinline__ void glds16(const void* g, void* l) {
    __builtin_amdgcn_global_load_lds(
        (const __attribute__((address_space(1))) void*)g,
        (__attribute__((address_space(3))) void*)l, 16, 0, 0);
}

// ---------------------------------------------------------------------------
// Fused prep: blocks [0,12288) convert Q/K/V fp32->fp16 (8 elems/thread);
// blocks [12288,15360) transpose+convert W[K][N] fp32 -> Wt[N][K] fp16.
__global__ __launch_bounds__(256) void prep(
        const float* __restrict__ Q, const float* __restrict__ K,
        const float* __restrict__ V,
        _Float16* __restrict__ qb, _Float16* __restrict__ kb, _Float16* __restrict__ vb,
        const float* __restrict__ Wq, const float* __restrict__ Wk,
        const float* __restrict__ Wv,
        _Float16* __restrict__ wqt, _Float16* __restrict__ wkt, _Float16* __restrict__ wvt) {
    __shared__ float t[32][33];
    int bid = blockIdx.x, tid = threadIdx.x;
    if (bid < 12288) {
        int ten = bid >> 12;              // 0,1,2
        int bx  = bid & 4095;
        const float* src = ten == 0 ? Q : (ten == 1 ? K : V);
        _Float16* dst    = ten == 0 ? qb : (ten == 1 ? kb : vb);
        size_t i = ((size_t)bx * 256 + tid) * 8;
        float4 a = *(const float4*)(src + i);
        float4 b = *(const float4*)(src + i + 4);
        half8 h;
        h[0] = (_Float16)a.x; h[1] = (_Float16)a.y; h[2] = (_Float16)a.z; h[3] = (_Float16)a.w;
        h[4] = (_Float16)b.x; h[5] = (_Float16)b.y; h[6] = (_Float16)b.z; h[7] = (_Float16)b.w;
        *(half8*)(dst + i) = h;
    } else {
        int wb = bid - 12288;             // [0, 3072)
        int z  = wb >> 10;                // 0,1,2
        int rem = wb & 1023;
        const float* W = z == 0 ? Wq : (z == 1 ? Wk : Wv);
        _Float16* Wt   = z == 0 ? wqt : (z == 1 ? wkt : wvt);
        int k0 = (rem & 31) * 32, n0 = (rem >> 5) * 32;
        int tx = tid & 31, ty = tid >> 5;
#pragma unroll
        for (int i = 0; i < 4; i++)
            t[ty + i * 8][tx] = W[(size_t)(k0 + ty + i * 8) * DM + n0 + tx];
        __syncthreads();
#pragma unroll
        for (int i = 0; i < 4; i++)
            Wt[(size_t)(n0 + ty + i * 8) * DM + k0 + tx] = (_Float16)t[tx][ty + i * 8];
    }
}

// ---------------------------------------------------------------------------
// Projection GEMM: C[8192,1024] = A[8192,1024] @ W[1024,1024] + bias.
// 256x256 tile, BK=64, 8 waves (2M x 4N, 512 thr), depth-1 pipeline:
// per K-tile two phases, each {stage 1/2 of tile t+1 via global_load_lds,
// ds_read frags, 32 MFMA}, then ONE __syncthreads (its vmcnt(0) drains loads
// issued 1-2 phases earlier -> latency mostly covered by compute).
// LDS 128KB (2 buf x (A 32KB + B 32KB)) -> 1 block/CU (8 waves, 2/SIMD).
// __launch_bounds__(512, 1): round-5's (512,2) resolved to a 128-VGPR cap
// (4 waves/SIMD budget) and spilled acc to scratch (WRITE_SIZE 179MB,
// MfmaUtil 9.5%). Demand ~215 VGPR needs the 256 cap -> second arg 1.
// grid (32, 4, 3). Swizzle identical to proven 128^2 scheme (rows extended):
// stage: LDS[row][c] = G[row][c ^ (row&7)]; read rows are 8k+l15 so
// pl = want ^ (l15&7) inverts it.
// z<2: swapped operands -> acc rows = d -> packed stores to [b][h][s][d].
// z=2: normal order -> acc rows = s -> packed stores to vT [b][h][d][s].
__global__ __launch_bounds__(512, 1) void proj_gemm(
        const _Float16* __restrict__ qb, const _Float16* __restrict__ kb,
        const _Float16* __restrict__ vb,
        const _Float16* __restrict__ wqt, const _Float16* __restrict__ wkt,
        const _Float16* __restrict__ wvt,
        const float* __restrict__ bq, const float* __restrict__ bk,
        const float* __restrict__ bv,
        _Float16* __restrict__ qh, _Float16* __restrict__ kh, _Float16* __restrict__ vT) {
    __shared__ _Float16 lds[65536];          // 128 KB
    _Float16* As = lds;                      // [2][256*64]
    _Float16* Bs = lds + 32768;              // [2][256*64]
    int z = blockIdx.z;
    const _Float16* A  = z == 0 ? qb : (z == 1 ? kb : vb);
    const _Float16* Bw = z == 0 ? wqt : (z == 1 ? wkt : wvt);
    const float* bias  = z == 0 ? bq : (z == 1 ? bk : bv);
    int m0 = blockIdx.x * 256, n0 = blockIdx.y * 256;
    int tid = threadIdx.x, wid = tid >> 6, lane = tid & 63;
    int l15 = lane & 15, quad = lane >> 4;
    int wm = wid >> 2, wn = wid & 3;         // 2M x 4N
    bool swapped = (z < 2);

    int srow = lane >> 3;                    // row within 8-row stage chunk
    int pg = (lane & 7) ^ srow;              // pre-swizzled source 16B chunk

    floatx4 acc[8][4] = {};                  // per-wave 128x64 output

    // ---- prologue: stage K-tile 0 into buf 0 ----
#pragma unroll
    for (int r = 0; r < 4; r++) {
        int rowA = r * 64 + wid * 8;
        glds16(A  + (size_t)(m0 + rowA + srow) * DM + pg * 8, &As[rowA * 64]);
        glds16(Bw + (size_t)(n0 + rowA + srow) * DM + pg * 8, &Bs[rowA * 64]);
    }
    __syncthreads();

    for (int t = 0; t < 16; t++) {
        int buf  = (t & 1) << 14;            // *16384
        int nbuf = buf ^ 16384;
        int kn0 = (t + 1) * 64;

        // ================= phase A =================
        if (t < 15) {
#pragma unroll
            for (int r = 0; r < 2; r++) {
                int rowA = r * 64 + wid * 8;
                glds16(A  + (size_t)(m0 + rowA + srow) * DM + kn0 + pg * 8,
                       &As[nbuf + rowA * 64]);
                glds16(Bw + (size_t)(n0 + rowA + srow) * DM + kn0 + pg * 8,
                       &Bs[nbuf + rowA * 64]);
            }
        }
        half8 bfr[4][2];                     // all B frags, held across both phases
#pragma unroll
        for (int nt = 0; nt < 4; nt++)
#pragma unroll
            for (int kc = 0; kc < 2; kc++) {
                int row = wn * 64 + nt * 16 + l15;
                int pl = (kc * 4 + quad) ^ (l15 & 7);
                bfr[nt][kc] = *(const half8*)&Bs[buf + row * 64 + pl * 8];
            }
        half8 afr[4][2];                     // A frags mt 0..3
#pragma unroll
        for (int mt = 0; mt < 4; mt++)
#pragma unroll
            for (int kc = 0; kc < 2; kc++) {
                int row = wm * 128 + mt * 16 + l15;
                int pl = (kc * 4 + quad) ^ (l15 & 7);
                afr[mt][kc] = *(const half8*)&As[buf + row * 64 + pl * 8];
            }
        if (swapped) {
#pragma unroll
            for (int kc = 0; kc < 2; kc++)
#pragma unroll
                for (int mt = 0; mt < 4; mt++)
#pragma unroll
                    for (int nt = 0; nt < 4; nt++)
                        acc[mt][nt] = __builtin_amdgcn_mfma_f32_16x16x32_f16(
                            bfr[nt][kc], afr[mt][kc], acc[mt][nt], 0, 0, 0);
        } else {
#pragma unroll
            for (int kc = 0; kc < 2; kc++)
#pragma unroll
                for (int mt = 0; mt < 4; mt++)
#pragma unroll
                    for (int nt = 0; nt < 4; nt++)
                        acc[mt][nt] = __builtin_amdgcn_mfma_f32_16x16x32_f16(
                            afr[mt][kc], bfr[nt][kc], acc[mt][nt], 0, 0, 0);
        }

        // ================= phase B =================
        if (t < 15) {
#pragma unroll
            for (int r = 2; r < 4; r++) {
                int rowA = r * 64 + wid * 8;
                glds16(A  + (size_t)(m0 + rowA + srow) * DM + kn0 + pg * 8,
                       &As[nbuf + rowA * 64]);
                glds16(Bw + (size_t)(n0 + rowA + srow) * DM + kn0 + pg * 8,
                       &Bs[nbuf + rowA * 64]);
            }
        }
#pragma unroll
        for (int mt = 0; mt < 4; mt++)       // A frags mt 4..7 (reuse regs)
#pragma unroll
            for (int kc = 0; kc < 2; kc++) {
                int row = wm * 128 + 64 + mt * 16 + l15;
                int pl = (kc * 4 + quad) ^ (l15 & 7);
                afr[mt][kc] = *(const half8*)&As[buf + row * 64 + pl * 8];
            }
        if (swapped) {
#pragma unroll
            for (int kc = 0; kc < 2; kc++)
#pragma unroll
                for (int mt = 0; mt < 4; mt++)
#pragma unroll
                    for (int nt = 0; nt < 4; nt++)
                        acc[4 + mt][nt] = __builtin_amdgcn_mfma_f32_16x16x32_f16(
                            bfr[nt][kc], afr[mt][kc], acc[4 + mt][nt], 0, 0, 0);
        } else {
#pragma unroll
            for (int kc = 0; kc < 2; kc++)
#pragma unroll
                for (int mt = 0; mt < 4; mt++)
#pragma unroll
                    for (int nt = 0; nt < 4; nt++)
                        acc[4 + mt][nt] = __builtin_amdgcn_mfma_f32_16x16x32_f16(
                            afr[mt][kc], bfr[nt][kc], acc[4 + mt][nt], 0, 0, 0);
        }

        __syncthreads();   // vmcnt(0)+lgkm drain: t+1 loads were issued 1-2
                           // phases ago -> mostly complete; buf swap safe
    }

    if (swapped) {
        // acc[mt][nt]: s = m0+wm*128+mt*16+l15 (lane col),
        //              d = n0+wn*64+nt*16+quad*4+r (rows, consecutive)
        float sc = (z == 0) ? 0.125f : 1.0f;
        _Float16* out = (z == 0) ? qh : kh;
#pragma unroll
        for (int nt = 0; nt < 4; nt++) {
            int d0 = n0 + wn * 64 + nt * 16 + quad * 4;
            int hh = d0 >> 6, dd = d0 & 63;
            floatx4 b4 = *(const floatx4*)&bias[d0];
#pragma unroll
            for (int mt = 0; mt < 8; mt++) {
                int s = m0 + wm * 128 + mt * 16 + l15;
                int b_ = s >> 10, ss = s & 1023;
                size_t off = ((size_t)(b_ * HEADS + hh)) * 65536 + (size_t)ss * 64 + dd;
                half4 hv;
#pragma unroll
                for (int r = 0; r < 4; r++)
                    hv[r] = (_Float16)((acc[mt][nt][r] + b4[r]) * sc);
                *(half4*)&out[off] = hv;
            }
        }
    } else {
        // acc[mt][nt]: d = n0+wn*64+nt*16+l15 (lane col),
        //              s = m0+wm*128+mt*16+quad*4+r (rows, consecutive)
#pragma unroll
        for (int nt = 0; nt < 4; nt++) {
            int d = n0 + wn * 64 + nt * 16 + l15;
            int hh = d >> 6, dd = d & 63;
            float bv_ = bias[d];
#pragma unroll
            for (int mt = 0; mt < 8; mt++) {
                int s0 = m0 + wm * 128 + mt * 16 + quad * 4;
                int b_ = s0 >> 10, ss = s0 & 1023;
                size_t off = ((size_t)(b_ * HEADS + hh)) * 65536 + (size_t)dd * 1024 + ss;
                half4 hv;
#pragma unroll
                for (int r = 0; r < 4; r++)
                    hv[r] = (_Float16)(acc[mt][nt][r] + bv_);
                *(half4*)&vT[off] = hv;
            }
        }
    }
}

// ---------------------------------------------------------------------------
// Attention: one block = 256 q-rows of one (b,h); 64 q-rows per wave.
// grid (4, 16, 8), block 256. S^T = K*Q^T so P-writes are packed ds_write_b64;
// P lives in the dead Q-tile LDS region (per-wave 64x64 tile).
// LDS: Ks 8KB + Vs 8KB + QP 32KB = 48 KB.
__global__ __launch_bounds__(256) void attn(
        const _Float16* __restrict__ qh, const _Float16* __restrict__ kh,
        const _Float16* __restrict__ vT, float* __restrict__ out) {
    __shared__ _Float16 Ks[4096];
    __shared__ _Float16 Vs[4096];
    __shared__ _Float16 QP[16384];
    int qt = blockIdx.x, h = blockIdx.y, b = blockIdx.z;
    size_t base = ((size_t)(b * HEADS + h)) * 65536;
    int tid = threadIdx.x, wid = tid >> 6, lane = tid & 63;
    int l15 = lane & 15, quad = lane >> 4;
    int rs = lane >> 3;
    int pg = (lane & 7) ^ rs;

    // stage Q tile [256][64]
#pragma unroll
    for (int ii = 0; ii < 8; ii++) {
        int issue = wid * 8 + ii;
        int r = issue * 8 + rs;
        glds16(qh + base + (size_t)(qt * 256 + r) * 64 + pg * 8, &QP[issue * 512]);
    }
    __syncthreads();
    half8 qf[4][2];
#pragma unroll
    for (int mt = 0; mt < 4; mt++)
#pragma unroll
        for (int kc = 0; kc < 2; kc++) {
            int row = wid * 64 + mt * 16 + l15;
            int pl = (kc * 4 + quad) ^ (l15 & 7);
            qf[mt][kc] = *(const half8*)&QP[row * 64 + pl * 8];
        }
    __syncthreads();   // all q-frag reads done before P overwrites the region

    floatx4 oacc[4][4] = {};
    float rden[4] = {0.f, 0.f, 0.f, 0.f};
    _Float16* Pw = &QP[wid * 4096];   // per-wave 64q x 64k P tile
                                      // layout: (k>>3)*512 + q*8 + (k&7)

    for (int kt = 0; kt < 16; kt++) {
        __syncthreads();
#pragma unroll
        for (int ii = 0; ii < 2; ii++) {
            int issue = wid * 2 + ii;
            int r = issue * 8 + rs;
            glds16(kh + base + (size_t)(kt * 64 + r) * 64 + pg * 8, &Ks[issue * 512]);
            glds16(vT + base + (size_t)r * 1024 + kt * 64 + pg * 8, &Vs[issue * 512]);
        }
        __syncthreads();

#pragma unroll
        for (int hf = 0; hf < 2; hf++) {
            // S^T = K * Q^T for 32 keys: D rows = key (consecutive), cols = query
            floatx4 sacc[2][4] = {};
#pragma unroll
            for (int kc = 0; kc < 2; kc++) {
                half8 kf[2];
#pragma unroll
                for (int kn2 = 0; kn2 < 2; kn2++) {
                    int kn = hf * 2 + kn2;
                    int pl = (kc * 4 + quad) ^ (l15 & 7);
                    kf[kn2] = *(const half8*)&Ks[(kn * 16 + l15) * 64 + pl * 8];
                }
#pragma unroll
                for (int kn2 = 0; kn2 < 2; kn2++)
#pragma unroll
                    for (int mt = 0; mt < 4; mt++)
                        sacc[kn2][mt] = __builtin_amdgcn_mfma_f32_16x16x32_f16(
                            kf[kn2], qf[mt][kc], sacc[kn2][mt], 0, 0, 0);
            }
            // exp + packed P write: element (key kn*16+quad*4+r, query mt*16+l15)
#pragma unroll
            for (int kn2 = 0; kn2 < 2; kn2++) {
                int kn = hf * 2 + kn2;
#pragma unroll
                for (int mt = 0; mt < 4; mt++) {
                    half4 ph;
#pragma unroll
                    for (int r = 0; r < 4; r++) {
                        float p = __expf(sacc[kn2][mt][r]);
                        rden[mt] += p;
                        ph[r] = (_Float16)p;
                    }
                    *(half4*)&Pw[(kn * 2 + (quad >> 1)) * 512 + (mt * 16 + l15) * 8 +
                                 (quad & 1) * 4] = ph;
                }
            }
            // O += P * V for these 32 keys
            half8 af[4], vf[4];
#pragma unroll
            for (int mt = 0; mt < 4; mt++)
                af[mt] = *(const half8*)&Pw[(hf * 4 + quad) * 512 + (mt * 16 + l15) * 8];
#pragma unroll
            for (int dn = 0; dn < 4; dn++) {
                int pl = (hf * 4 + quad) ^ (l15 & 7);
                vf[dn] = *(const half8*)&Vs[(dn * 16 + l15) * 64 + pl * 8];
            }
#pragma unroll
            for (int mt = 0; mt < 4; mt++)
#pragma unroll
                for (int dn = 0; dn < 4; dn++)
                    oacc[mt][dn] = __builtin_amdgcn_mfma_f32_16x16x32_f16(
                        af[mt], vf[dn], oacc[mt][dn], 0, 0, 0);
        }
    }

    // denominator: reduce across quads (each lane summed keys = quad*4+r pattern)
#pragma unroll
    for (int mt = 0; mt < 4; mt++) {
        float d = rden[mt];
        d += __shfl_xor(d, 16, 64);
        d += __shfl_xor(d, 32, 64);
        rden[mt] = 1.0f / (d + 1e-8f);
    }
    // oacc[mt][dn]: rows = q (mt*16+quad*4+r), cols = d (dn*16+l15)
#pragma unroll
    for (int mt = 0; mt < 4; mt++) {
#pragma unroll
        for (int r = 0; r < 4; r++) {
            float dinv = __shfl(rden[mt], quad * 4 + r, 16);
            int s = qt * 256 + wid * 64 + mt * 16 + quad * 4 + r;
#pragma unroll
            for (int dn = 0; dn < 4; dn++) {
                int col = h * 64 + dn * 16 + l15;
                out[((size_t)(b * SEQ + s)) * 1024 + col] = oacc[mt][dn][r] * dinv;
            }
        }
    }
}

// ---------------------------------------------------------------------------
extern "C" void kernel_launch(void* const* d_in, const int* in_sizes, int n_in,
                              void* d_out, int out_size, void* d_ws, size_t ws_size,
                              hipStream_t stream) {
    const float* Q  = (const float*)d_in[0];
    const float* K  = (const float*)d_in[1];
    const float* V  = (const float*)d_in[2];
    const float* Wq = (const float*)d_in[3];
    const float* bq = (const float*)d_in[4];
    const float* Wk = (const float*)d_in[5];
    const float* bk = (const float*)d_in[6];
    const float* Wv = (const float*)d_in[7];
    const float* bv = (const float*)d_in[8];
    float* out = (float*)d_out;

    char* ws = (char*)d_ws;
    const size_t TEN = (size_t)MTOT * DM * sizeof(_Float16);   // 16 MiB
    _Float16* qb  = (_Float16*)(ws);
    _Float16* kb  = (_Float16*)(ws + TEN);
    _Float16* vb  = (_Float16*)(ws + 2 * TEN);
    _Float16* qh  = (_Float16*)(ws + 3 * TEN);
    _Float16* kh  = (_Float16*)(ws + 4 * TEN);
    _Float16* vT  = (_Float16*)(ws + 5 * TEN);
    const size_t WTN = (size_t)DM * DM * sizeof(_Float16);     // 2 MiB
    _Float16* wqt = (_Float16*)(ws + 6 * TEN);
    _Float16* wkt = (_Float16*)(ws + 6 * TEN + WTN);
    _Float16* wvt = (_Float16*)(ws + 6 * TEN + 2 * WTN);

    prep<<<dim3(15360), 256, 0, stream>>>(Q, K, V, qb, kb, vb,
                                          Wq, Wk, Wv, wqt, wkt, wvt);
    proj_gemm<<<dim3(32, 4, 3), 512, 0, stream>>>(qb, kb, vb, wqt, wkt, wvt,
                                                  bq, bk, bv, qh, kh, vT);
    attn<<<dim3(4, 16, 8), 256, 0, stream>>>(qh, kh, vT, out);
}

// Round 7
// 276.744 us; speedup vs baseline: 1.4956x; 1.4956x over previous
//
#include <hip/hip_runtime.h>
#include <stdint.h>

#define DM 1024      // d_model
#define HEADS 16
#define BATCH 8
#define SEQ 1024
#define MTOT 8192    // BATCH*SEQ

typedef _Float16 half8 __attribute__((ext_vector_type(8)));
typedef _Float16 half4 __attribute__((ext_vector_type(4)));
typedef float floatx4 __attribute__((ext_vector_type(4)));

// async global->LDS, 16B per lane. lds dest must be wave-uniform base; HW adds lane*16.
__device__ __forceinline__ void glds16(const void* g, void* l) {
    __builtin_amdgcn_global_load_lds(
        (const __attribute__((address_space(1))) void*)g,
        (__attribute__((address_space(3))) void*)l, 16, 0, 0);
}

// ---------------------------------------------------------------------------
// Fused prep: blocks [0,12288) convert Q/K/V fp32->fp16 (8 elems/thread);
// blocks [12288,15360) transpose+convert W[K][N] fp32 -> Wt[N][K] fp16.
__global__ __launch_bounds__(256) void prep(
        const float* __restrict__ Q, const float* __restrict__ K,
        const float* __restrict__ V,
        _Float16* __restrict__ qb, _Float16* __restrict__ kb, _Float16* __restrict__ vb,
        const float* __restrict__ Wq, const float* __restrict__ Wk,
        const float* __restrict__ Wv,
        _Float16* __restrict__ wqt, _Float16* __restrict__ wkt, _Float16* __restrict__ wvt) {
    __shared__ float t[32][33];
    int bid = blockIdx.x, tid = threadIdx.x;
    if (bid < 12288) {
        int ten = bid >> 12;              // 0,1,2
        int bx  = bid & 4095;
        const float* src = ten == 0 ? Q : (ten == 1 ? K : V);
        _Float16* dst    = ten == 0 ? qb : (ten == 1 ? kb : vb);
        size_t i = ((size_t)bx * 256 + tid) * 8;
        float4 a = *(const float4*)(src + i);
        float4 b = *(const float4*)(src + i + 4);
        half8 h;
        h[0] = (_Float16)a.x; h[1] = (_Float16)a.y; h[2] = (_Float16)a.z; h[3] = (_Float16)a.w;
        h[4] = (_Float16)b.x; h[5] = (_Float16)b.y; h[6] = (_Float16)b.z; h[7] = (_Float16)b.w;
        *(half8*)(dst + i) = h;
    } else {
        int wb = bid - 12288;             // [0, 3072)
        int z  = wb >> 10;                // 0,1,2
        int rem = wb & 1023;
        const float* W = z == 0 ? Wq : (z == 1 ? Wk : Wv);
        _Float16* Wt   = z == 0 ? wqt : (z == 1 ? wkt : wvt);
        int k0 = (rem & 31) * 32, n0 = (rem >> 5) * 32;
        int tx = tid & 31, ty = tid >> 5;
#pragma unroll
        for (int i = 0; i < 4; i++)
            t[ty + i * 8][tx] = W[(size_t)(k0 + ty + i * 8) * DM + n0 + tx];
        __syncthreads();
#pragma unroll
        for (int i = 0; i < 4; i++)
            Wt[(size_t)(n0 + ty + i * 8) * DM + k0 + tx] = (_Float16)t[tx][ty + i * 8];
    }
}

// ---------------------------------------------------------------------------
// Projection GEMM: C[8192,1024] = A[8192,1024] @ W[1024,1024] + bias.
// grid (64, 8, 3), block 256 (4 waves, 2x2 of 64x64 each).
// Depth-1 pipelined, glds16-only staging (T3 minimum 2-phase):
//   per K-tile: issue 8 glds16 of tile t+1 into buf^1, then frag-read +
//   32 MFMA on buf, then ONE __syncthreads. The barrier's vmcnt(0) drains
//   loads issued ~16 ds_read_b128 + 32 MFMA earlier (covered), vs round-0's
//   zero-cover drain. LDS 64KB dbuf (occupancy was NOT the round-1 problem:
//   occ was equal 32KB vs 64KB; the reg-staged-A chain was).
// z<2: MFMA operand order swapped (A-op = W-frag) so accumulator rows = d
//      (consecutive) -> packed 8B stores to [b][h][s][d].
// z=2: original order, accumulator rows = s -> packed 8B stores to vT [b][h][d][s].
__global__ __launch_bounds__(256) void proj_gemm(
        const _Float16* __restrict__ qb, const _Float16* __restrict__ kb,
        const _Float16* __restrict__ vb,
        const _Float16* __restrict__ wqt, const _Float16* __restrict__ wkt,
        const _Float16* __restrict__ wvt,
        const float* __restrict__ bq, const float* __restrict__ bk,
        const float* __restrict__ bv,
        _Float16* __restrict__ qh, _Float16* __restrict__ kh, _Float16* __restrict__ vT) {
    __shared__ _Float16 As[2][128 * 64];
    __shared__ _Float16 Bs[2][128 * 64];
    int z = blockIdx.z;
    const _Float16* A  = z == 0 ? qb : (z == 1 ? kb : vb);
    const _Float16* Bw = z == 0 ? wqt : (z == 1 ? wkt : wvt);
    const float* bias  = z == 0 ? bq : (z == 1 ? bk : bv);
    int m0 = blockIdx.x * 128, n0 = blockIdx.y * 128;
    int tid = threadIdx.x, wid = tid >> 6, lane = tid & 63;
    int l15 = lane & 15, quad = lane >> 4;
    int wm = wid >> 1, wn = wid & 1;
    bool swapped = (z < 2);

    int rbase = wid * 32 + (lane >> 3);   // staged row: (wid*4+ii)*8 + (lane>>3)
    int pg = (lane & 7) ^ (lane >> 3);    // pre-swizzled global 16B chunk

    floatx4 acc[4][4] = {};

    // ---- prologue: stage K-tile 0 into buf 0 ----
#pragma unroll
    for (int ii = 0; ii < 4; ii++) {
        int rr = rbase + ii * 8;
        glds16(A  + (size_t)(m0 + rr) * DM + pg * 8, &As[0][(wid * 4 + ii) * 512]);
        glds16(Bw + (size_t)(n0 + rr) * DM + pg * 8, &Bs[0][(wid * 4 + ii) * 512]);
    }
    __syncthreads();

    for (int t = 0; t < 16; t++) {
        int cur = t & 1;

        // ---- issue next-tile stage first (latency hides under compute) ----
        if (t < 15) {
            int k0 = (t + 1) * 64;
#pragma unroll
            for (int ii = 0; ii < 4; ii++) {
                int rr = rbase + ii * 8;
                glds16(A  + (size_t)(m0 + rr) * DM + k0 + pg * 8,
                       &As[cur ^ 1][(wid * 4 + ii) * 512]);
                glds16(Bw + (size_t)(n0 + rr) * DM + k0 + pg * 8,
                       &Bs[cur ^ 1][(wid * 4 + ii) * 512]);
            }
        }

        // ---- compute current tile ----
#pragma unroll
        for (int kc = 0; kc < 2; kc++) {
            half8 a[4], b[4];
#pragma unroll
            for (int mt = 0; mt < 4; mt++) {
                int row = wm * 64 + mt * 16 + l15;
                int pl = (kc * 4 + quad) ^ (l15 & 7);
                a[mt] = *(const half8*)&As[cur][row * 64 + pl * 8];
            }
#pragma unroll
            for (int nt = 0; nt < 4; nt++) {
                int row = wn * 64 + nt * 16 + l15;
                int pl = (kc * 4 + quad) ^ (l15 & 7);
                b[nt] = *(const half8*)&Bs[cur][row * 64 + pl * 8];
            }
            if (swapped) {
#pragma unroll
                for (int mt = 0; mt < 4; mt++)
#pragma unroll
                    for (int nt = 0; nt < 4; nt++)
                        acc[mt][nt] = __builtin_amdgcn_mfma_f32_16x16x32_f16(
                            b[nt], a[mt], acc[mt][nt], 0, 0, 0);
            } else {
#pragma unroll
                for (int mt = 0; mt < 4; mt++)
#pragma unroll
                    for (int nt = 0; nt < 4; nt++)
                        acc[mt][nt] = __builtin_amdgcn_mfma_f32_16x16x32_f16(
                            a[mt], b[nt], acc[mt][nt], 0, 0, 0);
            }
        }

        __syncthreads();   // drains t+1 stage (issued pre-compute -> covered);
                           // also fences buf reuse for next iteration
    }

    if (swapped) {
        // acc[mt][nt]: element (s, d): s = m0+wm*64+mt*16+l15 (per-lane col),
        //                              d = n0+wn*64+nt*16+quad*4+r (rows, consecutive)
        float sc = (z == 0) ? 0.125f : 1.0f;
        _Float16* out = (z == 0) ? qh : kh;
#pragma unroll
        for (int nt = 0; nt < 4; nt++) {
            int d0 = n0 + wn * 64 + nt * 16 + quad * 4;
            int hh = d0 >> 6, dd = d0 & 63;
            floatx4 b4 = *(const floatx4*)&bias[d0];
#pragma unroll
            for (int mt = 0; mt < 4; mt++) {
                int s = m0 + wm * 64 + mt * 16 + l15;
                int b_ = s >> 10, ss = s & 1023;
                size_t off = ((size_t)(b_ * HEADS + hh)) * 65536 + (size_t)ss * 64 + dd;
                half4 hv;
#pragma unroll
                for (int r = 0; r < 4; r++)
                    hv[r] = (_Float16)((acc[mt][nt][r] + b4[r]) * sc);
                *(half4*)&out[off] = hv;
            }
        }
    } else {
        // acc[mt][nt]: element (s, d): d = n0+wn*64+nt*16+l15 (per-lane col),
        //                              s = m0+wm*64+mt*16+quad*4+r (rows, consecutive)
#pragma unroll
        for (int nt = 0; nt < 4; nt++) {
            int d = n0 + wn * 64 + nt * 16 + l15;
            int hh = d >> 6, dd = d & 63;
            float bv_ = bias[d];
#pragma unroll
            for (int mt = 0; mt < 4; mt++) {
                int s0 = m0 + wm * 64 + mt * 16 + quad * 4;
                int b_ = s0 >> 10, ss = s0 & 1023;
                size_t off = ((size_t)(b_ * HEADS + hh)) * 65536 + (size_t)dd * 1024 + ss;
                half4 hv;
#pragma unroll
                for (int r = 0; r < 4; r++)
                    hv[r] = (_Float16)(acc[mt][nt][r] + bv_);
                *(half4*)&vT[off] = hv;
            }
        }
    }
}

// ---------------------------------------------------------------------------
// Attention: one block = 256 q-rows of one (b,h); 64 q-rows per wave.
// grid (4, 16, 8), block 256. S^T = K*Q^T so P-writes are packed ds_write_b64;
// P lives in the dead Q-tile LDS region (per-wave 64x64 tile).
// LDS: Ks 8KB + Vs 8KB + QP 32KB = 48 KB.
__global__ __launch_bounds__(256) void attn(
        const _Float16* __restrict__ qh, const _Float16* __restrict__ kh,
        const _Float16* __restrict__ vT, float* __restrict__ out) {
    __shared__ _Float16 Ks[4096];
    __shared__ _Float16 Vs[4096];
    __shared__ _Float16 QP[16384];
    int qt = blockIdx.x, h = blockIdx.y, b = blockIdx.z;
    size_t base = ((size_t)(b * HEADS + h)) * 65536;
    int tid = threadIdx.x, wid = tid >> 6, lane = tid & 63;
    int l15 = lane & 15, quad = lane >> 4;
    int rs = lane >> 3;
    int pg = (lane & 7) ^ rs;

    // stage Q tile [256][64]
#pragma unroll
    for (int ii = 0; ii < 8; ii++) {
        int issue = wid * 8 + ii;
        int r = issue * 8 + rs;
        glds16(qh + base + (size_t)(qt * 256 + r) * 64 + pg * 8, &QP[issue * 512]);
    }
    __syncthreads();
    half8 qf[4][2];
#pragma unroll
    for (int mt = 0; mt < 4; mt++)
#pragma unroll
        for (int kc = 0; kc < 2; kc++) {
            int row = wid * 64 + mt * 16 + l15;
            int pl = (kc * 4 + quad) ^ (l15 & 7);
            qf[mt][kc] = *(const half8*)&QP[row * 64 + pl * 8];
        }
    __syncthreads();   // all q-frag reads done before P overwrites the region

    floatx4 oacc[4][4] = {};
    float rden[4] = {0.f, 0.f, 0.f, 0.f};
    _Float16* Pw = &QP[wid * 4096];   // per-wave 64q x 64k P tile
                                      // layout: (k>>3)*512 + q*8 + (k&7)

    for (int kt = 0; kt < 16; kt++) {
        __syncthreads();
#pragma unroll
        for (int ii = 0; ii < 2; ii++) {
            int issue = wid * 2 + ii;
            int r = issue * 8 + rs;
            glds16(kh + base + (size_t)(kt * 64 + r) * 64 + pg * 8, &Ks[issue * 512]);
            glds16(vT + base + (size_t)r * 1024 + kt * 64 + pg * 8, &Vs[issue * 512]);
        }
        __syncthreads();

#pragma unroll
        for (int hf = 0; hf < 2; hf++) {
            // S^T = K * Q^T for 32 keys: D rows = key (consecutive), cols = query
            floatx4 sacc[2][4] = {};
#pragma unroll
            for (int kc = 0; kc < 2; kc++) {
                half8 kf[2];
#pragma unroll
                for (int kn2 = 0; kn2 < 2; kn2++) {
                    int kn = hf * 2 + kn2;
                    int pl = (kc * 4 + quad) ^ (l15 & 7);
                    kf[kn2] = *(const half8*)&Ks[(kn * 16 + l15) * 64 + pl * 8];
                }
#pragma unroll
                for (int kn2 = 0; kn2 < 2; kn2++)
#pragma unroll
                    for (int mt = 0; mt < 4; mt++)
                        sacc[kn2][mt] = __builtin_amdgcn_mfma_f32_16x16x32_f16(
                            kf[kn2], qf[mt][kc], sacc[kn2][mt], 0, 0, 0);
            }
            // exp + packed P write: element (key kn*16+quad*4+r, query mt*16+l15)
#pragma unroll
            for (int kn2 = 0; kn2 < 2; kn2++) {
                int kn = hf * 2 + kn2;
#pragma unroll
                for (int mt = 0; mt < 4; mt++) {
                    half4 ph;
#pragma unroll
                    for (int r = 0; r < 4; r++) {
                        float p = __expf(sacc[kn2][mt][r]);
                        rden[mt] += p;
                        ph[r] = (_Float16)p;
                    }
                    *(half4*)&Pw[(kn * 2 + (quad >> 1)) * 512 + (mt * 16 + l15) * 8 +
                                 (quad & 1) * 4] = ph;
                }
            }
            // O += P * V for these 32 keys
            half8 af[4], vf[4];
#pragma unroll
            for (int mt = 0; mt < 4; mt++)
                af[mt] = *(const half8*)&Pw[(hf * 4 + quad) * 512 + (mt * 16 + l15) * 8];
#pragma unroll
            for (int dn = 0; dn < 4; dn++) {
                int pl = (hf * 4 + quad) ^ (l15 & 7);
                vf[dn] = *(const half8*)&Vs[(dn * 16 + l15) * 64 + pl * 8];
            }
#pragma unroll
            for (int mt = 0; mt < 4; mt++)
#pragma unroll
                for (int dn = 0; dn < 4; dn++)
                    oacc[mt][dn] = __builtin_amdgcn_mfma_f32_16x16x32_f16(
                        af[mt], vf[dn], oacc[mt][dn], 0, 0, 0);
        }
    }

    // denominator: reduce across quads (each lane summed keys = quad*4+r pattern)
#pragma unroll
    for (int mt = 0; mt < 4; mt++) {
        float d = rden[mt];
        d += __shfl_xor(d, 16, 64);
        d += __shfl_xor(d, 32, 64);
        rden[mt] = 1.0f / (d + 1e-8f);
    }
    // oacc[mt][dn]: rows = q (mt*16+quad*4+r), cols = d (dn*16+l15)
#pragma unroll
    for (int mt = 0; mt < 4; mt++) {
#pragma unroll
        for (int r = 0; r < 4; r++) {
            float dinv = __shfl(rden[mt], quad * 4 + r, 16);
            int s = qt * 256 + wid * 64 + mt * 16 + quad * 4 + r;
#pragma unroll
            for (int dn = 0; dn < 4; dn++) {
                int col = h * 64 + dn * 16 + l15;
                out[((size_t)(b * SEQ + s)) * 1024 + col] = oacc[mt][dn][r] * dinv;
            }
        }
    }
}

// ---------------------------------------------------------------------------
extern "C" void kernel_launch(void* const* d_in, const int* in_sizes, int n_in,
                              void* d_out, int out_size, void* d_ws, size_t ws_size,
                              hipStream_t stream) {
    const float* Q  = (const float*)d_in[0];
    const float* K  = (const float*)d_in[1];
    const float* V  = (const float*)d_in[2];
    const float* Wq = (const float*)d_in[3];
    const float* bq = (const float*)d_in[4];
    const float* Wk = (const float*)d_in[5];
    const float* bk = (const float*)d_in[6];
    const float* Wv = (const float*)d_in[7];
    const float* bv = (const float*)d_in[8];
    float* out = (float*)d_out;

    char* ws = (char*)d_ws;
    const size_t TEN = (size_t)MTOT * DM * sizeof(_Float16);   // 16 MiB
    _Float16* qb  = (_Float16*)(ws);
    _Float16* kb  = (_Float16*)(ws + TEN);
    _Float16* vb  = (_Float16*)(ws + 2 * TEN);
    _Float16* qh  = (_Float16*)(ws + 3 * TEN);
    _Float16* kh  = (_Float16*)(ws + 4 * TEN);
    _Float16* vT  = (_Float16*)(ws + 5 * TEN);
    const size_t WTN = (size_t)DM * DM * sizeof(_Float16);     // 2 MiB
    _Float16* wqt = (_Float16*)(ws + 6 * TEN);
    _Float16* wkt = (_Float16*)(ws + 6 * TEN + WTN);
    _Float16* wvt = (_Float16*)(ws + 6 * TEN + 2 * WTN);

    prep<<<dim3(15360), 256, 0, stream>>>(Q, K, V, qb, kb, vb,
                                          Wq, Wk, Wv, wqt, wkt, wvt);
    proj_gemm<<<dim3(64, 8, 3), 256, 0, stream>>>(qb, kb, vb, wqt, wkt, wvt,
                                                  bq, bk, bv, qh, kh, vT);
    attn<<<dim3(4, 16, 8), 256, 0, stream>>>(qh, kh, vT, out);
}